// Round 1
// baseline (280.442 us; speedup 1.0000x reference)
//
#include <hip/hip_runtime.h>
#include <math.h>

// Problem constants
#define B    64
#define S1   513
#define S    512      // CRF sequence length (S1 - 1)
#define H    768
#define T    4        // NLAB + 2
#define START 2
#define STOP  3

// d_out layout (floats), reference tuple order:
// (isqa_pred[64,1], crf_pred[64,512], isqa_loss, crf_loss, tags[64,512], IsQA[64,1])
#define OUT_ISQA_PRED 0
#define OUT_CRF_PRED  64
#define OUT_ISQA_LOSS 32832
#define OUT_CRF_LOSS  32833
#define OUT_TAGS      32834
#define OUT_ISQA      65602

// ws layout (floats): feats[B*S*T], isqa_logits[B*2], zg[B]
#define WS_FEATS  0
#define WS_LOGITS (B*S*T)           // 131072
#define WS_ZG     (B*S*T + 2*B)     // 131200
// total floats needed: 131264 (~525 KB)

// ---------------------------------------------------------------------------
// Kernel 1: feats = emb[:,1:] @ crf_W.T + crf_b  (wave-per-row, HBM-bound)
//           also isqa_logits = emb[:,0] @ fc2_W.T + fc2_b
// ---------------------------------------------------------------------------
__global__ __launch_bounds__(256) void feats_kernel(
    const float* __restrict__ emb,
    const float* __restrict__ fc2_W, const float* __restrict__ fc2_b,
    const float* __restrict__ crf_W, const float* __restrict__ crf_b,
    float* __restrict__ ws)
{
    __shared__ float wlds[(T + 2) * H];   // crf_W rows 0..3, then fc2_W rows 0..1
    for (int i = threadIdx.x; i < (T + 2) * H; i += 256) {
        wlds[i] = (i < T * H) ? crf_W[i] : fc2_W[i - T * H];
    }
    __syncthreads();

    const int wave = threadIdx.x >> 6;
    const int lane = threadIdx.x & 63;
    const int nw   = gridDim.x * 4;
    const float4* __restrict__ emb4 = (const float4*)emb;
    const float4* __restrict__ w4   = (const float4*)wlds;
    float* __restrict__ feats  = ws + WS_FEATS;
    float* __restrict__ logits = ws + WS_LOGITS;

    for (int r = blockIdx.x * 4 + wave; r < B * S1; r += nw) {
        const int b = r / S1;
        const int s = r - b * S1;
        const float4* __restrict__ row = emb4 + (size_t)r * (H / 4);

        float a0 = 0.f, a1 = 0.f, a2 = 0.f, a3 = 0.f;
        if (s != 0) {
            #pragma unroll
            for (int kk = 0; kk < 3; ++kk) {
                int k = lane + 64 * kk;
                float4 e  = row[k];
                float4 w0 = w4[0 * (H / 4) + k];
                float4 w1 = w4[1 * (H / 4) + k];
                float4 w2 = w4[2 * (H / 4) + k];
                float4 w3 = w4[3 * (H / 4) + k];
                a0 += e.x * w0.x + e.y * w0.y + e.z * w0.z + e.w * w0.w;
                a1 += e.x * w1.x + e.y * w1.y + e.z * w1.z + e.w * w1.w;
                a2 += e.x * w2.x + e.y * w2.y + e.z * w2.z + e.w * w2.w;
                a3 += e.x * w3.x + e.y * w3.y + e.z * w3.z + e.w * w3.w;
            }
        } else {
            #pragma unroll
            for (int kk = 0; kk < 3; ++kk) {
                int k = lane + 64 * kk;
                float4 e  = row[k];
                float4 w0 = w4[4 * (H / 4) + k];
                float4 w1 = w4[5 * (H / 4) + k];
                a0 += e.x * w0.x + e.y * w0.y + e.z * w0.z + e.w * w0.w;
                a1 += e.x * w1.x + e.y * w1.y + e.z * w1.z + e.w * w1.w;
            }
        }
        // wave reduce (64 lanes)
        #pragma unroll
        for (int m = 32; m; m >>= 1) {
            a0 += __shfl_xor(a0, m);
            a1 += __shfl_xor(a1, m);
            a2 += __shfl_xor(a2, m);
            a3 += __shfl_xor(a3, m);
        }
        if (lane == 0) {
            if (s != 0) {
                float4 o;
                o.x = a0 + crf_b[0]; o.y = a1 + crf_b[1];
                o.z = a2 + crf_b[2]; o.w = a3 + crf_b[3];
                ((float4*)feats)[b * S + (s - 1)] = o;
            } else {
                logits[b * 2 + 0] = a0 + fc2_b[0];
                logits[b * 2 + 1] = a1 + fc2_b[1];
            }
        }
    }
}

// ---------------------------------------------------------------------------
// Kernel 2: per-batch CRF: Z (log-partition), gold score, Viterbi + backtrack,
//           tags echo, IsQA echo. One wave per batch; lanes act as states
//           (j = lane & 3, redundant over 16 groups).
// ---------------------------------------------------------------------------
__device__ __forceinline__ unsigned int compose4(unsigned int a, unsigned int b)
{
    // maps {0..3}->{0..3} packed 2 bits/entry; result(x) = a[b[x]]
    unsigned int r = 0;
    #pragma unroll
    for (int x = 0; x < 4; ++x) {
        unsigned int bx = (b >> (2 * x)) & 3u;
        unsigned int ax = (a >> (2 * bx)) & 3u;
        r |= ax << (2 * x);
    }
    return r;
}

__global__ __launch_bounds__(64) void crf_kernel(
    const int* __restrict__ ans, const int* __restrict__ isqa,
    const float* __restrict__ trans,
    float* __restrict__ ws, float* __restrict__ out)
{
    __shared__ float sf[S * T];                 // 8 KB: this batch's feats
    __shared__ unsigned int bpw[S / 4];         // 512 backpointer bytes (t=0 = identity)

    const int b    = blockIdx.x;
    const int lane = threadIdx.x;
    const int j    = lane & 3;
    const int base = lane & ~3;

    // stage feats[b] into LDS
    {
        const float4* __restrict__ f4 = (const float4*)(ws + WS_FEATS + (size_t)b * S * T);
        float4* sf4 = (float4*)sf;
        #pragma unroll
        for (int k = 0; k < (S * T / 4) / 64; ++k)
            sf4[lane + 64 * k] = f4[lane + 64 * k];
    }
    // per-lane transition columns
    const float tc0 = trans[0 * T + j];
    const float tc1 = trans[1 * T + j];
    const float tc2 = trans[2 * T + j];
    const float tc3 = trans[3 * T + j];
    const float tsj = trans[START * T + j];   // trans[START][j]
    const float tjs = trans[j * T + STOP];    // trans[j][STOP]
    if (lane == 0) ((unsigned char*)bpw)[0] = 0xE4;   // identity map for t=0
    __syncthreads();

    // ---- gold score + tags echo (parallel over t) ----
    float g = 0.f;
    #pragma unroll
    for (int k = 0; k < S / 64; ++k) {
        const int t   = lane + 64 * k;
        const int tag = ans[b * S1 + 1 + t];
        out[OUT_TAGS + b * S + t] = (float)tag;
        g += sf[t * T + tag];
        if (t == 0) g += trans[START * T + tag];
        else        g += trans[ans[b * S1 + t] * T + tag];
        if (t == S - 1) g += trans[tag * T + STOP];
    }
    #pragma unroll
    for (int m = 32; m; m >>= 1) g += __shfl_xor(g, m);
    // g = gold score (all lanes)

    if (lane == 0) out[OUT_ISQA + b] = (float)isqa[b];

    // ---- fused alpha (logsumexp) + delta (viterbi) scan ----
    float alpha = sf[j] + tsj;
    float delta = alpha;
    for (int t = 1; t < S; ++t) {
        const float f  = sf[t * T + j];
        const float aa = alpha, dd = delta;
        const float a0 = __shfl(aa, base + 0);
        const float a1 = __shfl(aa, base + 1);
        const float a2 = __shfl(aa, base + 2);
        const float a3 = __shfl(aa, base + 3);
        const float x0 = a0 + tc0, x1 = a1 + tc1, x2 = a2 + tc2, x3 = a3 + tc3;
        const float m  = fmaxf(fmaxf(x0, x1), fmaxf(x2, x3));
        const float ss = __expf(x0 - m) + __expf(x1 - m) + __expf(x2 - m) + __expf(x3 - m);
        const float na = m + __logf(ss) + f;

        const float d0 = __shfl(dd, base + 0);
        const float d1 = __shfl(dd, base + 1);
        const float d2 = __shfl(dd, base + 2);
        const float d3 = __shfl(dd, base + 3);
        const float y0 = d0 + tc0, y1 = d1 + tc1, y2 = d2 + tc2, y3 = d3 + tc3;
        float bestv = y0; unsigned int besti = 0;
        if (y1 > bestv) { bestv = y1; besti = 1; }
        if (y2 > bestv) { bestv = y2; besti = 2; }
        if (y3 > bestv) { bestv = y3; besti = 3; }
        const float nd = bestv + f;

        const unsigned int p0 = __shfl(besti, base + 0);
        const unsigned int p1 = __shfl(besti, base + 1);
        const unsigned int p2 = __shfl(besti, base + 2);
        const unsigned int p3 = __shfl(besti, base + 3);
        if (lane == 0)
            ((unsigned char*)bpw)[t] = (unsigned char)(p0 | (p1 << 2) | (p2 << 4) | (p3 << 6));

        alpha = na; delta = nd;
    }

    // ---- Z = logsumexp_j(alpha + trans[j][STOP]) ----
    {
        const float zj = alpha + tjs;
        const float z0 = __shfl(zj, base + 0);
        const float z1 = __shfl(zj, base + 1);
        const float z2 = __shfl(zj, base + 2);
        const float z3 = __shfl(zj, base + 3);
        const float m  = fmaxf(fmaxf(z0, z1), fmaxf(z2, z3));
        const float Z  = m + __logf(__expf(z0 - m) + __expf(z1 - m) +
                                    __expf(z2 - m) + __expf(z3 - m));
        if (lane == 0) ws[WS_ZG + b] = Z - g;
    }

    // ---- last_tag = argmax_j(delta + trans[j][STOP]) (first-index wins) ----
    unsigned int last_tag;
    {
        const float vj = delta + tjs;
        const float v0 = __shfl(vj, base + 0);
        const float v1 = __shfl(vj, base + 1);
        const float v2 = __shfl(vj, base + 2);
        const float v3 = __shfl(vj, base + 3);
        float bv = v0; last_tag = 0;
        if (v1 > bv) { bv = v1; last_tag = 1; }
        if (v2 > bv) { bv = v2; last_tag = 2; }
        if (v3 > bv) { bv = v3; last_tag = 3; }
    }

    __syncthreads();   // bpw visible

    // ---- backtrack via associative map composition ----
    // byte t holds f_t: tag_t -> tag_{t-1}. tag_t = (f_{t+1}∘...∘f_{511})(last_tag)
    const unsigned int w0 = bpw[lane * 2 + 0];   // bytes 8L..8L+3
    const unsigned int w1 = bpw[lane * 2 + 1];   // bytes 8L+4..8L+7
    // chunk map G_L = f_{8L} ∘ f_{8L+1} ∘ ... ∘ f_{8L+7}
    unsigned int Gm = (w1 >> 24) & 0xFFu;        // f_{8L+7}
    #pragma unroll
    for (int k = 6; k >= 0; --k) {
        const unsigned int fk = ((k < 4 ? (w0 >> (8 * k)) : (w1 >> (8 * (k - 4)))) & 0xFFu);
        Gm = compose4(fk, Gm);
    }
    // inclusive suffix scan: S_L = G_L ∘ G_{L+1} ∘ ... ∘ G_63
    unsigned int Sm = Gm;
    #pragma unroll
    for (int d = 1; d < 64; d <<= 1) {
        const unsigned int oth = __shfl(Sm, (lane + d) & 63);
        if (lane + d < 64) Sm = compose4(Sm, oth);
    }
    // exclusive: e_map = S_{L+1} (identity for lane 63); tag at t = 8L+7
    unsigned int emap = __shfl(Sm, (lane + 1) & 63);
    if (lane == 63) emap = 0xE4u;
    unsigned int cur = (emap >> (2 * last_tag)) & 3u;

    float tg[8];
    tg[7] = (float)cur;
    #pragma unroll
    for (int k = 7; k >= 1; --k) {
        const unsigned int fk = ((k < 4 ? (w0 >> (8 * k)) : (w1 >> (8 * (k - 4)))) & 0xFFu);
        cur = (fk >> (2 * cur)) & 3u;
        tg[k - 1] = (float)cur;
    }
    #pragma unroll
    for (int k = 0; k < 8; ++k)
        out[OUT_CRF_PRED + b * S + lane * 8 + k] = tg[k];
}

// ---------------------------------------------------------------------------
// Kernel 3: reductions — crf_loss, isqa_loss, isqa_pred
// ---------------------------------------------------------------------------
__global__ __launch_bounds__(64) void final_kernel(
    const int* __restrict__ isqa, const float* __restrict__ ws,
    float* __restrict__ out)
{
    const int lane = threadIdx.x;          // = batch index
    const float zg = ws[WS_ZG + lane];
    const float l0 = ws[WS_LOGITS + lane * 2 + 0];
    const float l1 = ws[WS_LOGITS + lane * 2 + 1];
    const float m  = fmaxf(l0, l1);
    const float lse = m + __logf(__expf(l0 - m) + __expf(l1 - m));
    const int   y   = isqa[lane];
    const float li  = lse - (y ? l1 : l0);

    float s1 = zg, s2 = li;
    #pragma unroll
    for (int d = 32; d; d >>= 1) {
        s1 += __shfl_xor(s1, d);
        s2 += __shfl_xor(s2, d);
    }
    out[OUT_ISQA_PRED + lane] = (l1 > l0) ? 1.0f : 0.0f;
    if (lane == 0) {
        out[OUT_CRF_LOSS]  = s1 * (1.0f / 64.0f);
        out[OUT_ISQA_LOSS] = s2 * (1.0f / 64.0f);
    }
}

// ---------------------------------------------------------------------------
extern "C" void kernel_launch(void* const* d_in, const int* in_sizes, int n_in,
                              void* d_out, int out_size, void* d_ws, size_t ws_size,
                              hipStream_t stream)
{
    const float* emb    = (const float*)d_in[0];   // (64,513,768) f32
    const int*   ans    = (const int*)d_in[1];     // (64,513) i32
    const int*   isqa   = (const int*)d_in[2];     // (64,) i32
    const float* fc2_W  = (const float*)d_in[3];   // (2,768)
    const float* fc2_b  = (const float*)d_in[4];   // (2,)
    const float* crf_W  = (const float*)d_in[5];   // (4,768)
    const float* crf_b  = (const float*)d_in[6];   // (4,)
    const float* trans  = (const float*)d_in[7];   // (4,4)
    float* out = (float*)d_out;
    float* ws  = (float*)d_ws;

    feats_kernel<<<513, 256, 0, stream>>>(emb, fc2_W, fc2_b, crf_W, crf_b, ws);
    crf_kernel<<<64, 64, 0, stream>>>(ans, isqa, trans, ws, out);
    final_kernel<<<1, 64, 0, stream>>>(isqa, ws, out);
}

// Round 2
// 215.032 us; speedup vs baseline: 1.3042x; 1.3042x over previous
//
#include <hip/hip_runtime.h>
#include <math.h>

// Problem constants
#define B     64
#define S1    513
#define S     512
#define H     768
#define T     4
#define START 2
#define STOP  3

// d_out layout (floats), reference tuple order:
// (isqa_pred[64,1], crf_pred[64,512], isqa_loss, crf_loss, tags[64,512], IsQA[64,1])
#define OUT_ISQA_PRED 0
#define OUT_CRF_PRED  64
#define OUT_ISQA_LOSS 32832
#define OUT_CRF_LOSS  32833
#define OUT_TAGS      32834
#define OUT_ISQA      65602

// ws layout (floats): feats[B*S*T], isqa_logits[B*2], zg[B]
#define WS_FEATS  0
#define WS_LOGITS (B*S*T)           // 131072
#define WS_ZG     (B*S*T + 2*B)     // 131200

// ---------------------------------------------------------------------------
// DPP helpers (quad_perm: broadcast / butterfly within groups of 4 lanes)
// ---------------------------------------------------------------------------
template<int CTRL>
__device__ __forceinline__ float dppf(float x) {
    int v = __builtin_amdgcn_update_dpp(__builtin_bit_cast(int, x),
                                        __builtin_bit_cast(int, x),
                                        CTRL, 0xF, 0xF, false);
    return __builtin_bit_cast(float, v);
}
// quad broadcasts: lane k of quad -> all: ctrl = k*0x55
// quad butterfly pairs: [1,0,3,2]=0xB1, [2,3,0,1]=0x4E

__device__ __forceinline__ float lse4(float x0, float x1, float x2, float x3) {
    float m = fmaxf(fmaxf(x0, x1), fmaxf(x2, x3));
    return m + __logf(__expf(x0 - m) + __expf(x1 - m) +
                      __expf(x2 - m) + __expf(x3 - m));
}

// ---------------------------------------------------------------------------
// Kernel 1: feats = emb[:,1:] @ crf_W.T + crf_b ; logits = emb[:,0] @ fc2_W.T
// 8 lanes per row -> 4104 waves (16 waves/CU) for deep memory pipelining.
// ---------------------------------------------------------------------------
__global__ __launch_bounds__(256) void feats_kernel(
    const float* __restrict__ emb,
    const float* __restrict__ fc2_W, const float* __restrict__ fc2_b,
    const float* __restrict__ crf_W, const float* __restrict__ crf_b,
    float* __restrict__ ws)
{
    __shared__ float wlds[6 * H];   // crf_W rows 0..3, fc2_W rows 0..1 (18 KB)
    for (int i = threadIdx.x; i < 6 * H; i += 256)
        wlds[i] = (i < 4 * H) ? crf_W[i] : fc2_W[i - 4 * H];
    __syncthreads();

    const int tid  = threadIdx.x;
    const int lane = tid & 63;
    const int l8   = lane & 7;
    const int gw   = blockIdx.x * 4 + (tid >> 6);   // 0..4103
    const int r    = gw * 8 + (lane >> 3);          // 0..32831 (exact)
    const int b    = r / S1;
    const int s    = r - b * S1;

    const float4* __restrict__ row4 = (const float4*)emb + (size_t)r * (H / 4);
    const float4* __restrict__ wl4  = (const float4*)wlds;
    const int o0 = s ? 0 * 192 : 4 * 192;
    const int o1 = s ? 1 * 192 : 5 * 192;
    const int o2 = s ? 2 * 192 : 4 * 192;   // kept in-bounds for s==0 (unused)
    const int o3 = s ? 3 * 192 : 5 * 192;

    float a0 = 0.f, a1 = 0.f, a2 = 0.f, a3 = 0.f;
    #pragma unroll 8
    for (int k = 0; k < 24; ++k) {
        const int idx = l8 + 8 * k;
        float4 e  = row4[idx];
        float4 w0 = wl4[o0 + idx];
        float4 w1 = wl4[o1 + idx];
        float4 w2 = wl4[o2 + idx];
        float4 w3 = wl4[o3 + idx];
        a0 += e.x * w0.x + e.y * w0.y + e.z * w0.z + e.w * w0.w;
        a1 += e.x * w1.x + e.y * w1.y + e.z * w1.z + e.w * w1.w;
        a2 += e.x * w2.x + e.y * w2.y + e.z * w2.z + e.w * w2.w;
        a3 += e.x * w3.x + e.y * w3.y + e.z * w3.z + e.w * w3.w;
    }
    // reduce across 8 lanes: quad butterfly (DPP) + xor-4 shuffle
    a0 += dppf<0xB1>(a0); a0 += dppf<0x4E>(a0); a0 += __shfl_xor(a0, 4);
    a1 += dppf<0xB1>(a1); a1 += dppf<0x4E>(a1); a1 += __shfl_xor(a1, 4);
    a2 += dppf<0xB1>(a2); a2 += dppf<0x4E>(a2); a2 += __shfl_xor(a2, 4);
    a3 += dppf<0xB1>(a3); a3 += dppf<0x4E>(a3); a3 += __shfl_xor(a3, 4);

    if (l8 == 0) {
        if (s) {
            float4 o;
            o.x = a0 + crf_b[0]; o.y = a1 + crf_b[1];
            o.z = a2 + crf_b[2]; o.w = a3 + crf_b[3];
            ((float4*)(ws + WS_FEATS))[b * S + (s - 1)] = o;
        } else {
            ws[WS_LOGITS + 2 * b + 0] = a0 + fc2_b[0];
            ws[WS_LOGITS + 2 * b + 1] = a1 + fc2_b[1];
        }
    }
}

// ---------------------------------------------------------------------------
// Kernel 2: grid 80. Blocks 0..63: per-batch Z (chunked log-semiring scan),
// gold score, tags echo, IsQA echo. Blocks 64..79: 4 batches each, bit-exact
// sequential Viterbi (DPP quad broadcasts) + v_perm map-composition backtrack.
// ---------------------------------------------------------------------------
__global__ __launch_bounds__(256) void crf_kernel(
    const int* __restrict__ ans, const int* __restrict__ isqa,
    const float* __restrict__ trans,
    float* __restrict__ ws, float* __restrict__ out)
{
    __shared__ float smemf[10240];   // 40 KB (union of Z and V usage)
    const int tid = threadIdx.x;
    const int blk = blockIdx.x;

    if (blk < 64) {
        // ================= Z-block: batch b =================
        const int b = blk;
        float* sf  = smemf;            // 2048 floats
        float* C   = smemf + 2048;     // 64 chunk matrices x 16
        float* red = smemf + 3072;     // 4 floats

        float tr[16];
        #pragma unroll
        for (int i = 0; i < 16; ++i) tr[i] = trans[i];

        {   // stage feats[b]
            float4* sf4 = (float4*)sf;
            const float4* src4 = (const float4*)(ws + WS_FEATS) + b * 512;
            sf4[tid] = src4[tid];
            sf4[tid + 256] = src4[tid + 256];
        }
        __syncthreads();

        // ---- gold score + tags echo ----
        float g = 0.f;
        #pragma unroll
        for (int u = 0; u < 2; ++u) {
            const int t   = 2 * tid + u;
            const int tag = ans[b * S1 + 1 + t];
            out[OUT_TAGS + b * S + t] = (float)tag;
            g += sf[t * 4 + tag];
            g += (t == 0) ? tr[START * 4 + tag] : tr[ans[b * S1 + t] * 4 + tag];
            if (t == S - 1) g += tr[tag * 4 + STOP];
        }
        #pragma unroll
        for (int m = 32; m; m >>= 1) g += __shfl_xor(g, m);
        if ((tid & 63) == 0) red[tid >> 6] = g;

        // ---- Phase A: chunk matrices, thread (c,jr) owns row jr of chunk c ----
        const int c  = tid >> 2;
        const int jr = tid & 3;
        const int t0 = c ? 8 * c : 1;
        float rl[4];
        #pragma unroll
        for (int i = 0; i < 4; ++i) rl[i] = tr[jr * 4 + i] + sf[t0 * 4 + i];
        for (int t = t0 + 1; t <= 8 * c + 7; ++t) {
            const float f0 = sf[t*4+0], f1 = sf[t*4+1], f2 = sf[t*4+2], f3 = sf[t*4+3];
            float nr[4];
            #pragma unroll
            for (int i = 0; i < 4; ++i)
                nr[i] = lse4(rl[0] + tr[0*4+i], rl[1] + tr[1*4+i],
                             rl[2] + tr[2*4+i], rl[3] + tr[3*4+i]);
            rl[0] = nr[0] + f0; rl[1] = nr[1] + f1;
            rl[2] = nr[2] + f2; rl[3] = nr[3] + f3;
        }
        ((float4*)C)[c * 4 + jr] = make_float4(rl[0], rl[1], rl[2], rl[3]);
        __syncthreads();

        // ---- Hillis-Steele inclusive scan over 64 chunk matrices ----
        for (int d = 1; d <= 32; d <<= 1) {
            const int cs = (c >= d) ? (c - d) : c;
            float4 ar = ((float4*)C)[cs * 4 + jr];
            float4 b0 = ((float4*)C)[c * 4 + 0];
            float4 b1 = ((float4*)C)[c * 4 + 1];
            float4 b2 = ((float4*)C)[c * 4 + 2];
            float4 b3 = ((float4*)C)[c * 4 + 3];
            __syncthreads();
            if (c >= d) {
                float4 nr;
                nr.x = lse4(ar.x + b0.x, ar.y + b1.x, ar.z + b2.x, ar.w + b3.x);
                nr.y = lse4(ar.x + b0.y, ar.y + b1.y, ar.z + b2.y, ar.w + b3.y);
                nr.z = lse4(ar.x + b0.z, ar.y + b1.z, ar.z + b2.z, ar.w + b3.z);
                nr.w = lse4(ar.x + b0.w, ar.y + b1.w, ar.z + b2.w, ar.w + b3.w);
                ((float4*)C)[c * 4 + jr] = nr;
            }
            __syncthreads();
        }

        if (tid == 0) {
            const float gold = red[0] + red[1] + red[2] + red[3];
            float a0k[4];
            #pragma unroll
            for (int k = 0; k < 4; ++k) a0k[k] = sf[k] + tr[START * 4 + k];
            const float* P = C + 63 * 16;   // P[k*4+i]
            float aN[4];
            #pragma unroll
            for (int i = 0; i < 4; ++i)
                aN[i] = lse4(a0k[0] + P[0*4+i], a0k[1] + P[1*4+i],
                             a0k[2] + P[2*4+i], a0k[3] + P[3*4+i]);
            const float Z = lse4(aN[0] + tr[0*4+STOP], aN[1] + tr[1*4+STOP],
                                 aN[2] + tr[2*4+STOP], aN[3] + tr[3*4+STOP]);
            ws[WS_ZG + b] = Z - gold;
            out[OUT_ISQA + b] = (float)isqa[b];
        }
    } else {
        // ================= V-block: batches 4*(blk-64) .. +3 =================
        const int bv = blk - 64;
        float* sfw = smemf;                                   // 4 x 2048 floats
        unsigned int* bpw = (unsigned int*)(smemf + 8192);    // 4 x 512 words
        {
            float4* d4 = (float4*)sfw;
            const float4* s4 = (const float4*)(ws + WS_FEATS) + bv * 4 * 512;
            #pragma unroll
            for (int n = 0; n < 8; ++n) d4[tid + 256 * n] = s4[tid + 256 * n];
        }
        if (tid < 4) bpw[tid * 512] = 0x03020100u;   // identity map at t=0
        __syncthreads();

        const int w    = tid >> 6;
        const int lane = tid & 63;
        const int j    = lane & 3;
        const int b    = bv * 4 + w;
        const float* myf = sfw + w * 2048;
        unsigned char* mybp = (unsigned char*)(bpw + w * 512);

        const float tc0 = trans[0*4+j], tc1 = trans[1*4+j];
        const float tc2 = trans[2*4+j], tc3 = trans[3*4+j];
        const float tjs = trans[j*4 + STOP];

        // exact sequential Viterbi (same fp32 op order as reference)
        float d = myf[j] + trans[START * 4 + j];
        float fcur = myf[4 + j];
        for (int t = 1; t < 512; ++t) {
            const float fnext = myf[(t + 1) * 4 + j];   // t=511 pad-read (in smem)
            const float d0 = dppf<0x00>(d), d1 = dppf<0x55>(d);
            const float d2 = dppf<0xAA>(d), d3 = dppf<0xFF>(d);
            const float y0 = d0 + tc0, y1 = d1 + tc1;
            const float y2 = d2 + tc2, y3 = d3 + tc3;
            float bv01 = y0; int bi01 = 0;
            if (y1 > bv01) { bv01 = y1; bi01 = 1; }
            float bv23 = y2; int bi23 = 2;
            if (y3 > bv23) { bv23 = y3; bi23 = 3; }
            float bvv = bv01; int bi = bi01;
            if (bv23 > bvv) { bvv = bv23; bi = bi23; }
            d = bvv + fcur;
            fcur = fnext;
            if (lane < 4) mybp[t * 4 + j] = (unsigned char)bi;
        }

        // last_tag (first-index-wins argmax over states)
        const float vj = d + tjs;
        const float z0 = dppf<0x00>(vj), z1 = dppf<0x55>(vj);
        const float z2 = dppf<0xAA>(vj), z3 = dppf<0xFF>(vj);
        float m01 = z0; unsigned int i01 = 0;
        if (z1 > m01) { m01 = z1; i01 = 1; }
        float m23 = z2; unsigned int i23 = 2;
        if (z3 > m23) { m23 = z3; i23 = 3; }
        const unsigned int lt = (m23 > m01) ? i23 : i01;

        __syncthreads();

        // backtrack: chunk map composition via v_perm_b32
        const uint4 wv0 = ((const uint4*)(bpw + w * 512))[lane * 2 + 0]; // t=8L..8L+3
        const uint4 wv1 = ((const uint4*)(bpw + w * 512))[lane * 2 + 1]; // t=8L+4..8L+7
        unsigned int wk[8] = {wv0.x, wv0.y, wv0.z, wv0.w, wv1.x, wv1.y, wv1.z, wv1.w};
        unsigned int G = wk[7];
        #pragma unroll
        for (int k = 6; k >= 0; --k)
            G = __builtin_amdgcn_perm(0u, wk[k], G);     // f_k ∘ G
        unsigned int Sm = G;
        #pragma unroll
        for (int dd = 1; dd < 64; dd <<= 1) {
            const int srcl = lane + dd;
            const unsigned int oth = __shfl(Sm, (srcl < 64) ? srcl : 63);
            if (srcl < 64) Sm = __builtin_amdgcn_perm(0u, Sm, oth);  // Sm ∘ oth
        }
        unsigned int emap = __shfl(Sm, (lane < 63) ? lane + 1 : 63);
        if (lane == 63) emap = 0x03020100u;
        unsigned int cur = (emap >> (8 * lt)) & 3u;

        float tg[8];
        tg[7] = (float)cur;
        #pragma unroll
        for (int k = 7; k >= 1; --k) {
            cur = (wk[k] >> (8 * cur)) & 3u;
            tg[k - 1] = (float)cur;
        }
        float4* op = (float4*)(out + OUT_CRF_PRED + b * S + lane * 8);
        op[0] = make_float4(tg[0], tg[1], tg[2], tg[3]);
        op[1] = make_float4(tg[4], tg[5], tg[6], tg[7]);
    }
}

// ---------------------------------------------------------------------------
// Kernel 3: reductions — crf_loss, isqa_loss, isqa_pred
// ---------------------------------------------------------------------------
__global__ __launch_bounds__(64) void final_kernel(
    const int* __restrict__ isqa, const float* __restrict__ ws,
    float* __restrict__ out)
{
    const int lane = threadIdx.x;          // = batch index
    const float zg = ws[WS_ZG + lane];
    const float l0 = ws[WS_LOGITS + lane * 2 + 0];
    const float l1 = ws[WS_LOGITS + lane * 2 + 1];
    const float m  = fmaxf(l0, l1);
    const float lse = m + __logf(__expf(l0 - m) + __expf(l1 - m));
    const int   y   = isqa[lane];
    const float li  = lse - (y ? l1 : l0);

    float s1 = zg, s2 = li;
    #pragma unroll
    for (int d = 32; d; d >>= 1) {
        s1 += __shfl_xor(s1, d);
        s2 += __shfl_xor(s2, d);
    }
    out[OUT_ISQA_PRED + lane] = (l1 > l0) ? 1.0f : 0.0f;
    if (lane == 0) {
        out[OUT_CRF_LOSS]  = s1 * (1.0f / 64.0f);
        out[OUT_ISQA_LOSS] = s2 * (1.0f / 64.0f);
    }
}

// ---------------------------------------------------------------------------
extern "C" void kernel_launch(void* const* d_in, const int* in_sizes, int n_in,
                              void* d_out, int out_size, void* d_ws, size_t ws_size,
                              hipStream_t stream)
{
    const float* emb    = (const float*)d_in[0];
    const int*   ans    = (const int*)d_in[1];
    const int*   isqa   = (const int*)d_in[2];
    const float* fc2_W  = (const float*)d_in[3];
    const float* fc2_b  = (const float*)d_in[4];
    const float* crf_W  = (const float*)d_in[5];
    const float* crf_b  = (const float*)d_in[6];
    const float* trans  = (const float*)d_in[7];
    float* out = (float*)d_out;
    float* ws  = (float*)d_ws;

    feats_kernel<<<1026, 256, 0, stream>>>(emb, fc2_W, fc2_b, crf_W, crf_b, ws);
    crf_kernel<<<80, 256, 0, stream>>>(ans, isqa, trans, ws, out);
    final_kernel<<<1, 64, 0, stream>>>(isqa, ws, out);
}

// Round 3
// 210.396 us; speedup vs baseline: 1.3329x; 1.0220x over previous
//
#include <hip/hip_runtime.h>
#include <math.h>

// Problem constants
#define B     64
#define S1    513
#define S     512
#define H     768
#define T     4
#define START 2
#define STOP  3

// d_out layout (floats), reference tuple order:
// (isqa_pred[64,1], crf_pred[64,512], isqa_loss, crf_loss, tags[64,512], IsQA[64,1])
#define OUT_ISQA_PRED 0
#define OUT_CRF_PRED  64
#define OUT_ISQA_LOSS 32832
#define OUT_CRF_LOSS  32833
#define OUT_TAGS      32834
#define OUT_ISQA      65602

// ws layout (floats): feats[B*S*T], isqa_logits[B*2], zg[B], done-counter
#define WS_FEATS  0
#define WS_LOGITS (B*S*T)           // 131072
#define WS_ZG     (B*S*T + 2*B)     // 131200
#define WS_CNT    (B*S*T + 3*B)     // 131264 (int)

// ---------------------------------------------------------------------------
// DPP helpers (quad_perm broadcasts/butterflies within groups of 4 lanes)
// ---------------------------------------------------------------------------
template<int CTRL>
__device__ __forceinline__ float dppf(float x) {
    int v = __builtin_amdgcn_update_dpp(__builtin_bit_cast(int, x),
                                        __builtin_bit_cast(int, x),
                                        CTRL, 0xF, 0xF, false);
    return __builtin_bit_cast(float, v);
}

__device__ __forceinline__ float lse4(float x0, float x1, float x2, float x3) {
    float m = fmaxf(fmaxf(x0, x1), fmaxf(x2, x3));
    return m + __logf(__expf(x0 - m) + __expf(x1 - m) +
                      __expf(x2 - m) + __expf(x3 - m));
}

// ---------------------------------------------------------------------------
// Kernel 1: feats = emb[:,1:] @ crf_W.T + crf_b ; logits = emb[:,0] @ fc2_W.T
// 16 lanes/row, 4 rows/wave, grid 2052 -> 8208 waves; launch_bounds(256,6)
// caps VGPRs so ~6 waves/SIMD materialize for deep memory pipelining.
// ---------------------------------------------------------------------------
__global__ __launch_bounds__(256, 6) void feats_kernel(
    const float* __restrict__ emb,
    const float* __restrict__ fc2_W, const float* __restrict__ fc2_b,
    const float* __restrict__ crf_W, const float* __restrict__ crf_b,
    float* __restrict__ ws)
{
    __shared__ float wlds[6 * H];   // crf_W rows 0..3, fc2_W rows 0..1 (18 KB)
    for (int i = threadIdx.x; i < 6 * H; i += 256)
        wlds[i] = (i < 4 * H) ? crf_W[i] : fc2_W[i - 4 * H];
    if (blockIdx.x == 0 && threadIdx.x == 0)
        ((int*)ws)[WS_CNT] = 0;     // zero the crf completion counter
    __syncthreads();

    const int tid  = threadIdx.x;
    const int lane = tid & 63;
    const int l16  = lane & 15;
    const int gw   = blockIdx.x * 4 + (tid >> 6);   // 0..8207
    const int r    = gw * 4 + (lane >> 4);          // 0..32831 (exact cover)
    const int b    = r / S1;
    const int s    = r - b * S1;

    const float4* __restrict__ row4 = (const float4*)emb + (size_t)r * (H / 4);
    const float4* __restrict__ wl4  = (const float4*)wlds;
    const int o0 = s ? 0 * 192 : 4 * 192;
    const int o1 = s ? 1 * 192 : 5 * 192;
    const int o2 = s ? 2 * 192 : 4 * 192;   // in-bounds dummy for s==0
    const int o3 = s ? 3 * 192 : 5 * 192;

    float a0 = 0.f, a1 = 0.f, a2 = 0.f, a3 = 0.f;
    #pragma unroll 4
    for (int k = 0; k < 12; ++k) {
        const int idx = l16 + 16 * k;
        float4 e  = row4[idx];
        float4 w0 = wl4[o0 + idx];
        float4 w1 = wl4[o1 + idx];
        float4 w2 = wl4[o2 + idx];
        float4 w3 = wl4[o3 + idx];
        a0 += e.x * w0.x + e.y * w0.y + e.z * w0.z + e.w * w0.w;
        a1 += e.x * w1.x + e.y * w1.y + e.z * w1.z + e.w * w1.w;
        a2 += e.x * w2.x + e.y * w2.y + e.z * w2.z + e.w * w2.w;
        a3 += e.x * w3.x + e.y * w3.y + e.z * w3.z + e.w * w3.w;
    }
    // reduce across 16 lanes: DPP quad butterflies + xor-4/xor-8 shuffles
    a0 += dppf<0xB1>(a0); a0 += dppf<0x4E>(a0);
    a1 += dppf<0xB1>(a1); a1 += dppf<0x4E>(a1);
    a2 += dppf<0xB1>(a2); a2 += dppf<0x4E>(a2);
    a3 += dppf<0xB1>(a3); a3 += dppf<0x4E>(a3);
    a0 += __shfl_xor(a0, 4); a0 += __shfl_xor(a0, 8);
    a1 += __shfl_xor(a1, 4); a1 += __shfl_xor(a1, 8);
    a2 += __shfl_xor(a2, 4); a2 += __shfl_xor(a2, 8);
    a3 += __shfl_xor(a3, 4); a3 += __shfl_xor(a3, 8);

    if (l16 == 0) {
        if (s) {
            float4 o;
            o.x = a0 + crf_b[0]; o.y = a1 + crf_b[1];
            o.z = a2 + crf_b[2]; o.w = a3 + crf_b[3];
            ((float4*)(ws + WS_FEATS))[b * S + (s - 1)] = o;
        } else {
            ws[WS_LOGITS + 2 * b + 0] = a0 + fc2_b[0];
            ws[WS_LOGITS + 2 * b + 1] = a1 + fc2_b[1];
        }
    }
}

// ---------------------------------------------------------------------------
// Kernel 2: grid 80. Blocks 0..63: per-batch Z (chunked log-semiring scan),
// gold score, tags echo, IsQA echo; last Z-block to finish also computes the
// final losses + isqa_pred. Blocks 64..79: 4 batches each, bit-exact
// sequential Viterbi (DPP quad broadcasts) + v_perm map-composition backtrack.
// ---------------------------------------------------------------------------
__global__ __launch_bounds__(256) void crf_kernel(
    const int* __restrict__ ans, const int* __restrict__ isqa,
    const float* __restrict__ trans,
    float* __restrict__ ws, float* __restrict__ out)
{
    __shared__ float smemf[10240];   // 40 KB (union of Z and V usage)
    __shared__ int isLast;
    const int tid = threadIdx.x;
    const int blk = blockIdx.x;

    if (blk < 64) {
        // ================= Z-block: batch b =================
        const int b = blk;
        float* sf  = smemf;            // 2048 floats
        float* C   = smemf + 2048;     // 64 chunk matrices x 16
        float* red = smemf + 3072;     // 4 floats

        float tr[16];
        #pragma unroll
        for (int i = 0; i < 16; ++i) tr[i] = trans[i];

        {   // stage feats[b]
            float4* sf4 = (float4*)sf;
            const float4* src4 = (const float4*)(ws + WS_FEATS) + b * 512;
            sf4[tid] = src4[tid];
            sf4[tid + 256] = src4[tid + 256];
        }
        __syncthreads();

        // ---- gold score + tags echo ----
        float g = 0.f;
        #pragma unroll
        for (int u = 0; u < 2; ++u) {
            const int t   = 2 * tid + u;
            const int tag = ans[b * S1 + 1 + t];
            out[OUT_TAGS + b * S + t] = (float)tag;
            g += sf[t * 4 + tag];
            g += (t == 0) ? tr[START * 4 + tag] : tr[ans[b * S1 + t] * 4 + tag];
            if (t == S - 1) g += tr[tag * 4 + STOP];
        }
        #pragma unroll
        for (int m = 32; m; m >>= 1) g += __shfl_xor(g, m);
        if ((tid & 63) == 0) red[tid >> 6] = g;

        // ---- Phase A: chunk matrices, thread (c,jr) owns row jr of chunk c ----
        const int c  = tid >> 2;
        const int jr = tid & 3;
        const int t0 = c ? 8 * c : 1;
        float rl[4];
        #pragma unroll
        for (int i = 0; i < 4; ++i) rl[i] = tr[jr * 4 + i] + sf[t0 * 4 + i];
        for (int t = t0 + 1; t <= 8 * c + 7; ++t) {
            const float f0 = sf[t*4+0], f1 = sf[t*4+1], f2 = sf[t*4+2], f3 = sf[t*4+3];
            float nr[4];
            #pragma unroll
            for (int i = 0; i < 4; ++i)
                nr[i] = lse4(rl[0] + tr[0*4+i], rl[1] + tr[1*4+i],
                             rl[2] + tr[2*4+i], rl[3] + tr[3*4+i]);
            rl[0] = nr[0] + f0; rl[1] = nr[1] + f1;
            rl[2] = nr[2] + f2; rl[3] = nr[3] + f3;
        }
        ((float4*)C)[c * 4 + jr] = make_float4(rl[0], rl[1], rl[2], rl[3]);
        __syncthreads();

        // ---- Hillis-Steele inclusive scan over 64 chunk matrices ----
        for (int d = 1; d <= 32; d <<= 1) {
            const int cs = (c >= d) ? (c - d) : c;
            float4 ar = ((float4*)C)[cs * 4 + jr];
            float4 b0 = ((float4*)C)[c * 4 + 0];
            float4 b1 = ((float4*)C)[c * 4 + 1];
            float4 b2 = ((float4*)C)[c * 4 + 2];
            float4 b3 = ((float4*)C)[c * 4 + 3];
            __syncthreads();
            if (c >= d) {
                float4 nr;
                nr.x = lse4(ar.x + b0.x, ar.y + b1.x, ar.z + b2.x, ar.w + b3.x);
                nr.y = lse4(ar.x + b0.y, ar.y + b1.y, ar.z + b2.y, ar.w + b3.y);
                nr.z = lse4(ar.x + b0.z, ar.y + b1.z, ar.z + b2.z, ar.w + b3.z);
                nr.w = lse4(ar.x + b0.w, ar.y + b1.w, ar.z + b2.w, ar.w + b3.w);
                ((float4*)C)[c * 4 + jr] = nr;
            }
            __syncthreads();
        }

        if (tid == 0) {
            const float gold = red[0] + red[1] + red[2] + red[3];
            float a0k[4];
            #pragma unroll
            for (int k = 0; k < 4; ++k) a0k[k] = sf[k] + tr[START * 4 + k];
            const float* P = C + 63 * 16;   // P[k*4+i]
            float aN[4];
            #pragma unroll
            for (int i = 0; i < 4; ++i)
                aN[i] = lse4(a0k[0] + P[0*4+i], a0k[1] + P[1*4+i],
                             a0k[2] + P[2*4+i], a0k[3] + P[3*4+i]);
            const float Z = lse4(aN[0] + tr[0*4+STOP], aN[1] + tr[1*4+STOP],
                                 aN[2] + tr[2*4+STOP], aN[3] + tr[3*4+STOP]);
            ws[WS_ZG + b] = Z - gold;
            out[OUT_ISQA + b] = (float)isqa[b];
            __threadfence();                 // release zg before counter inc
            const int old = atomicAdd((int*)ws + WS_CNT, 1);
            isLast = (old == 63);
        }
        __syncthreads();

        // ---- finisher: last Z-block computes losses + isqa_pred ----
        if (isLast && tid < 64) {
            __threadfence();                 // acquire all blocks' zg
            const float zg = ws[WS_ZG + tid];
            const float l0 = ws[WS_LOGITS + tid * 2 + 0];
            const float l1 = ws[WS_LOGITS + tid * 2 + 1];
            const float m  = fmaxf(l0, l1);
            const float lse = m + __logf(__expf(l0 - m) + __expf(l1 - m));
            const int   y   = isqa[tid];
            const float li  = lse - (y ? l1 : l0);
            float s1 = zg, s2 = li;
            #pragma unroll
            for (int d = 32; d; d >>= 1) {
                s1 += __shfl_xor(s1, d);
                s2 += __shfl_xor(s2, d);
            }
            out[OUT_ISQA_PRED + tid] = (l1 > l0) ? 1.0f : 0.0f;
            if (tid == 0) {
                out[OUT_CRF_LOSS]  = s1 * (1.0f / 64.0f);
                out[OUT_ISQA_LOSS] = s2 * (1.0f / 64.0f);
            }
        }
    } else {
        // ================= V-block: batches 4*(blk-64) .. +3 =================
        const int bv = blk - 64;
        float* sfw = smemf;                                   // 4 x 2048 floats
        unsigned int* bpw = (unsigned int*)(smemf + 8192);    // 4 x 512 words
        {
            float4* d4 = (float4*)sfw;
            const float4* s4 = (const float4*)(ws + WS_FEATS) + bv * 4 * 512;
            #pragma unroll
            for (int n = 0; n < 8; ++n) d4[tid + 256 * n] = s4[tid + 256 * n];
        }
        if (tid < 4) bpw[tid * 512] = 0x03020100u;   // identity map at t=0
        __syncthreads();

        const int w    = tid >> 6;
        const int lane = tid & 63;
        const int j    = lane & 3;
        const int b    = bv * 4 + w;
        const float* myf = sfw + w * 2048;
        unsigned char* mybp = (unsigned char*)(bpw + w * 512);

        const float tc0 = trans[0*4+j], tc1 = trans[1*4+j];
        const float tc2 = trans[2*4+j], tc3 = trans[3*4+j];
        const float tjs = trans[j*4 + STOP];

        // exact sequential Viterbi (same fp32 op order as reference)
        float d = myf[j] + trans[START * 4 + j];
        float fcur = myf[4 + j];
        for (int t = 1; t < 512; ++t) {
            const float fnext = myf[(t + 1) * 4 + j];   // t=511 pad-read (in smem)
            const float d0 = dppf<0x00>(d), d1 = dppf<0x55>(d);
            const float d2 = dppf<0xAA>(d), d3 = dppf<0xFF>(d);
            const float y0 = d0 + tc0, y1 = d1 + tc1;
            const float y2 = d2 + tc2, y3 = d3 + tc3;
            float bv01 = y0; int bi01 = 0;
            if (y1 > bv01) { bv01 = y1; bi01 = 1; }
            float bv23 = y2; int bi23 = 2;
            if (y3 > bv23) { bv23 = y3; bi23 = 3; }
            float bvv = bv01; int bi = bi01;
            if (bv23 > bvv) { bvv = bv23; bi = bi23; }
            d = bvv + fcur;
            fcur = fnext;
            if (lane < 4) mybp[t * 4 + j] = (unsigned char)bi;
        }

        // last_tag (first-index-wins argmax over states)
        const float vj = d + tjs;
        const float z0 = dppf<0x00>(vj), z1 = dppf<0x55>(vj);
        const float z2 = dppf<0xAA>(vj), z3 = dppf<0xFF>(vj);
        float m01 = z0; unsigned int i01 = 0;
        if (z1 > m01) { m01 = z1; i01 = 1; }
        float m23 = z2; unsigned int i23 = 2;
        if (z3 > m23) { m23 = z3; i23 = 3; }
        const unsigned int lt = (m23 > m01) ? i23 : i01;

        __syncthreads();

        // backtrack: chunk map composition via v_perm_b32
        const uint4 wv0 = ((const uint4*)(bpw + w * 512))[lane * 2 + 0]; // t=8L..8L+3
        const uint4 wv1 = ((const uint4*)(bpw + w * 512))[lane * 2 + 1]; // t=8L+4..8L+7
        unsigned int wk[8] = {wv0.x, wv0.y, wv0.z, wv0.w, wv1.x, wv1.y, wv1.z, wv1.w};
        unsigned int G = wk[7];
        #pragma unroll
        for (int k = 6; k >= 0; --k)
            G = __builtin_amdgcn_perm(0u, wk[k], G);     // f_k ∘ G
        unsigned int Sm = G;
        #pragma unroll
        for (int dd = 1; dd < 64; dd <<= 1) {
            const int srcl = lane + dd;
            const unsigned int oth = __shfl(Sm, (srcl < 64) ? srcl : 63);
            if (srcl < 64) Sm = __builtin_amdgcn_perm(0u, Sm, oth);  // Sm ∘ oth
        }
        unsigned int emap = __shfl(Sm, (lane < 63) ? lane + 1 : 63);
        if (lane == 63) emap = 0x03020100u;
        unsigned int cur = (emap >> (8 * lt)) & 3u;

        float tg[8];
        tg[7] = (float)cur;
        #pragma unroll
        for (int k = 7; k >= 1; --k) {
            cur = (wk[k] >> (8 * cur)) & 3u;
            tg[k - 1] = (float)cur;
        }
        float4* op = (float4*)(out + OUT_CRF_PRED + b * S + lane * 8);
        op[0] = make_float4(tg[0], tg[1], tg[2], tg[3]);
        op[1] = make_float4(tg[4], tg[5], tg[6], tg[7]);
    }
}

// ---------------------------------------------------------------------------
extern "C" void kernel_launch(void* const* d_in, const int* in_sizes, int n_in,
                              void* d_out, int out_size, void* d_ws, size_t ws_size,
                              hipStream_t stream)
{
    const float* emb    = (const float*)d_in[0];
    const int*   ans    = (const int*)d_in[1];
    const int*   isqa   = (const int*)d_in[2];
    const float* fc2_W  = (const float*)d_in[3];
    const float* fc2_b  = (const float*)d_in[4];
    const float* crf_W  = (const float*)d_in[5];
    const float* crf_b  = (const float*)d_in[6];
    const float* trans  = (const float*)d_in[7];
    float* out = (float*)d_out;
    float* ws  = (float*)d_ws;

    feats_kernel<<<2052, 256, 0, stream>>>(emb, fc2_W, fc2_b, crf_W, crf_b, ws);
    crf_kernel<<<80, 256, 0, stream>>>(ans, isqa, trans, ws, out);
}

// Round 4
// 195.100 us; speedup vs baseline: 1.4374x; 1.0784x over previous
//
#include <hip/hip_runtime.h>
#include <math.h>

// Problem constants
#define B     64
#define S1    513
#define S     512
#define H     768
#define T     4
#define START 2
#define STOP  3

// d_out layout (floats), reference tuple order:
// (isqa_pred[64,1], crf_pred[64,512], isqa_loss, crf_loss, tags[64,512], IsQA[64,1])
#define OUT_ISQA_PRED 0
#define OUT_CRF_PRED  64
#define OUT_ISQA_LOSS 32832
#define OUT_CRF_LOSS  32833
#define OUT_TAGS      32834
#define OUT_ISQA      65602

// ws layout (floats)
#define WS_FEATS  0                  // [B][S][T]  normal layout
#define WS_LOGITS (B*S*T)            // 131072: [B][2]
#define WS_ZG     (B*S*T + 2*B)      // 131200: [B]
#define WS_CNT    (B*S*T + 3*B)      // 131264: int counter
#define WS_FEATST 131280             // [B][T][S] transposed layout (131072 floats)

// ---------------------------------------------------------------------------
// DPP helpers (quad_perm broadcasts/butterflies within groups of 4 lanes)
// ---------------------------------------------------------------------------
template<int CTRL>
__device__ __forceinline__ float dppf(float x) {
    int v = __builtin_amdgcn_update_dpp(__builtin_bit_cast(int, x),
                                        __builtin_bit_cast(int, x),
                                        CTRL, 0xF, 0xF, false);
    return __builtin_bit_cast(float, v);
}
template<int CTRL>
__device__ __forceinline__ int dppi(int x) {
    return __builtin_amdgcn_update_dpp(x, x, CTRL, 0xF, 0xF, false);
}

__device__ __forceinline__ float lse4(float x0, float x1, float x2, float x3) {
    float m = fmaxf(fmaxf(x0, x1), fmaxf(x2, x3));
    return m + __logf(__expf(x0 - m) + __expf(x1 - m) +
                      __expf(x2 - m) + __expf(x3 - m));
}

// full-wave sum reduction: DPP xor1/xor2 + shfl xor4..32 (result in all lanes)
__device__ __forceinline__ float wred(float a) {
    a += dppf<0xB1>(a); a += dppf<0x4E>(a);
    a += __shfl_xor(a, 4); a += __shfl_xor(a, 8);
    a += __shfl_xor(a, 16); a += __shfl_xor(a, 32);
    return a;
}

// ---------------------------------------------------------------------------
// Kernel 1: feats = emb[:,1:] @ crf_W.T + crf_b
// 64 lanes/row, crf_W entirely in registers (12 float4/lane), no LDS in loop.
// Writes normal layout [b][t][4] and transposed layout [b][j][t].
// grid 1024x256 -> 4096 waves, 8 rows/wave grid-stride.
// ---------------------------------------------------------------------------
__global__ __launch_bounds__(256) void feats_kernel(
    const float* __restrict__ emb,
    const float* __restrict__ crf_W, const float* __restrict__ crf_b,
    float* __restrict__ ws)
{
    if (blockIdx.x == 0 && threadIdx.x == 0)
        ((int*)ws)[WS_CNT] = 0;      // zero crf completion counter

    const int tid  = threadIdx.x;
    const int lane = tid & 63;
    const int wid  = blockIdx.x * 4 + (tid >> 6);   // 0..4095

    const float4* __restrict__ W4 = (const float4*)crf_W;  // [4][192]
    float4 wr[4][3];
    #pragma unroll
    for (int o = 0; o < 4; ++o)
        #pragma unroll
        for (int k = 0; k < 3; ++k)
            wr[o][k] = W4[o * 192 + lane + 64 * k];
    const float cb0 = crf_b[0], cb1 = crf_b[1], cb2 = crf_b[2], cb3 = crf_b[3];

    float* __restrict__ fN = ws + WS_FEATS;
    float* __restrict__ fT = ws + WS_FEATST;

    #pragma unroll
    for (int i = 0; i < 8; ++i) {
        const int row = wid + 4096 * i;             // 0..32767
        const int b   = row >> 9;
        const int s   = (row & 511) + 1;
        const float4* __restrict__ src4 =
            (const float4*)emb + (size_t)(b * S1 + s) * (H / 4);

        float a0 = 0.f, a1 = 0.f, a2 = 0.f, a3 = 0.f;
        #pragma unroll
        for (int k = 0; k < 3; ++k) {
            const float4 e = src4[lane + 64 * k];
            a0 += e.x * wr[0][k].x + e.y * wr[0][k].y + e.z * wr[0][k].z + e.w * wr[0][k].w;
            a1 += e.x * wr[1][k].x + e.y * wr[1][k].y + e.z * wr[1][k].z + e.w * wr[1][k].w;
            a2 += e.x * wr[2][k].x + e.y * wr[2][k].y + e.z * wr[2][k].z + e.w * wr[2][k].w;
            a3 += e.x * wr[3][k].x + e.y * wr[3][k].y + e.z * wr[3][k].z + e.w * wr[3][k].w;
        }
        a0 = wred(a0); a1 = wred(a1); a2 = wred(a2); a3 = wred(a3);

        if (lane == 0) {
            const float v0 = a0 + cb0, v1 = a1 + cb1, v2 = a2 + cb2, v3 = a3 + cb3;
            ((float4*)fN)[b * S + (s - 1)] = make_float4(v0, v1, v2, v3);
            const int tb = b * 4 * S + (s - 1);
            fT[tb + 0 * S] = v0;
            fT[tb + 1 * S] = v1;
            fT[tb + 2 * S] = v2;
            fT[tb + 3 * S] = v3;
        }
    }
}

// ---------------------------------------------------------------------------
// Viterbi step: bit-exact value path (max of exact sums + add), first-index
// argmax; returns quad-packed map word (byte j = argmax for state j).
// ---------------------------------------------------------------------------
__device__ __forceinline__ unsigned int vstep(
    float& d, float fv,
    float tc0, float tc1, float tc2, float tc3, int sh8j)
{
    const float d0 = dppf<0x00>(d), d1 = dppf<0x55>(d);
    const float d2 = dppf<0xAA>(d), d3 = dppf<0xFF>(d);
    const float y0 = d0 + tc0, y1 = d1 + tc1;
    const float y2 = d2 + tc2, y3 = d3 + tc3;
    const float m01 = fmaxf(y0, y1), m23 = fmaxf(y2, y3);
    const int   i01 = (y1 > y0) ? 1 : 0;
    const int   i23 = (y3 > y2) ? 3 : 2;
    const int   bi  = (m23 > m01) ? i23 : i01;
    d = fmaxf(m01, m23) + fv;
    unsigned int mb = (unsigned int)bi << sh8j;      // byte slot j
    unsigned int t1 = mb | (unsigned int)dppi<0xB1>((int)mb);
    return t1 | (unsigned int)dppi<0x4E>((int)t1);
}

// ---------------------------------------------------------------------------
// Kernel 2: grid 80.
// Blocks 0..63 (Z): per-batch log-partition (chunked log-semiring scan), gold
//   score, tags echo, IsQA echo, fc2 logits; last block computes final losses.
// Blocks 64..79 (V): 4 batches each; bit-exact sequential Viterbi with
//   transposed-LDS b128 feats prefetch + packed backpointers; map-composition
//   backtrack.
// ---------------------------------------------------------------------------
__global__ __launch_bounds__(256) void crf_kernel(
    const int* __restrict__ ans, const int* __restrict__ isqa,
    const float* __restrict__ emb,
    const float* __restrict__ fc2_W, const float* __restrict__ fc2_b,
    const float* __restrict__ trans,
    float* __restrict__ ws, float* __restrict__ out)
{
    __shared__ float smemf[10784];   // V: sfT 8192 + pad 16 + bpw 2048 words
    __shared__ int isLast;
    const int tid = threadIdx.x;
    const int blk = blockIdx.x;

    if (blk < 64) {
        // ================= Z-block: batch b =================
        const int b = blk;
        float* sf  = smemf;            // 2048 floats
        float* C   = smemf + 2048;     // 64 chunk matrices x 16
        float* red = smemf + 3072;     // 4 floats

        float tr[16];
        #pragma unroll
        for (int i = 0; i < 16; ++i) tr[i] = trans[i];

        {   // stage feats[b] (normal layout)
            float4* sf4 = (float4*)sf;
            const float4* src4 = (const float4*)(ws + WS_FEATS) + b * 512;
            sf4[tid] = src4[tid];
            sf4[tid + 256] = src4[tid + 256];
        }

        // ---- fc2 logits for this batch (waves 0,1), independent of LDS ----
        if (tid < 128) {
            const int wv   = tid >> 6;       // 0 or 1
            const int lane = tid & 63;
            const float4* e4 = (const float4*)emb + (size_t)b * S1 * (H / 4);
            const float4* w4 = (const float4*)fc2_W + wv * 192;
            float acc = 0.f;
            #pragma unroll
            for (int k = 0; k < 3; ++k) {
                const float4 e = e4[lane + 64 * k];
                const float4 w = w4[lane + 64 * k];
                acc += e.x * w.x + e.y * w.y + e.z * w.z + e.w * w.w;
            }
            acc = wred(acc);
            if (lane == 0) {
                ws[WS_LOGITS + 2 * b + wv] = acc + fc2_b[wv];
                __threadfence();             // release this store device-wide
            }
        }
        __syncthreads();

        // ---- gold score + tags echo ----
        float g = 0.f;
        #pragma unroll
        for (int u = 0; u < 2; ++u) {
            const int t   = 2 * tid + u;
            const int tag = ans[b * S1 + 1 + t];
            out[OUT_TAGS + b * S + t] = (float)tag;
            g += sf[t * 4 + tag];
            g += (t == 0) ? tr[START * 4 + tag] : tr[ans[b * S1 + t] * 4 + tag];
            if (t == S - 1) g += tr[tag * 4 + STOP];
        }
        #pragma unroll
        for (int m = 32; m; m >>= 1) g += __shfl_xor(g, m);
        if ((tid & 63) == 0) red[tid >> 6] = g;

        // ---- Phase A: chunk matrices, thread (c,jr) owns row jr of chunk c ----
        const int c  = tid >> 2;
        const int jr = tid & 3;
        const int t0 = c ? 8 * c : 1;
        float rl[4];
        #pragma unroll
        for (int i = 0; i < 4; ++i) rl[i] = tr[jr * 4 + i] + sf[t0 * 4 + i];
        for (int t = t0 + 1; t <= 8 * c + 7; ++t) {
            const float f0 = sf[t*4+0], f1 = sf[t*4+1], f2 = sf[t*4+2], f3 = sf[t*4+3];
            float nr[4];
            #pragma unroll
            for (int i = 0; i < 4; ++i)
                nr[i] = lse4(rl[0] + tr[0*4+i], rl[1] + tr[1*4+i],
                             rl[2] + tr[2*4+i], rl[3] + tr[3*4+i]);
            rl[0] = nr[0] + f0; rl[1] = nr[1] + f1;
            rl[2] = nr[2] + f2; rl[3] = nr[3] + f3;
        }
        ((float4*)C)[c * 4 + jr] = make_float4(rl[0], rl[1], rl[2], rl[3]);
        __syncthreads();

        // ---- Hillis-Steele inclusive scan over 64 chunk matrices ----
        for (int d = 1; d <= 32; d <<= 1) {
            const int cs = (c >= d) ? (c - d) : c;
            float4 ar = ((float4*)C)[cs * 4 + jr];
            float4 b0 = ((float4*)C)[c * 4 + 0];
            float4 b1 = ((float4*)C)[c * 4 + 1];
            float4 b2 = ((float4*)C)[c * 4 + 2];
            float4 b3 = ((float4*)C)[c * 4 + 3];
            __syncthreads();
            if (c >= d) {
                float4 nr;
                nr.x = lse4(ar.x + b0.x, ar.y + b1.x, ar.z + b2.x, ar.w + b3.x);
                nr.y = lse4(ar.x + b0.y, ar.y + b1.y, ar.z + b2.y, ar.w + b3.y);
                nr.z = lse4(ar.x + b0.z, ar.y + b1.z, ar.z + b2.z, ar.w + b3.z);
                nr.w = lse4(ar.x + b0.w, ar.y + b1.w, ar.z + b2.w, ar.w + b3.w);
                ((float4*)C)[c * 4 + jr] = nr;
            }
            __syncthreads();
        }

        if (tid == 0) {
            const float gold = red[0] + red[1] + red[2] + red[3];
            float a0k[4];
            #pragma unroll
            for (int k = 0; k < 4; ++k) a0k[k] = sf[k] + tr[START * 4 + k];
            const float* P = C + 63 * 16;   // P[k*4+i]
            float aN[4];
            #pragma unroll
            for (int i = 0; i < 4; ++i)
                aN[i] = lse4(a0k[0] + P[0*4+i], a0k[1] + P[1*4+i],
                             a0k[2] + P[2*4+i], a0k[3] + P[3*4+i]);
            const float Z = lse4(aN[0] + tr[0*4+STOP], aN[1] + tr[1*4+STOP],
                                 aN[2] + tr[2*4+STOP], aN[3] + tr[3*4+STOP]);
            ws[WS_ZG + b] = Z - gold;
            out[OUT_ISQA + b] = (float)isqa[b];
            __threadfence();                 // release zg before counter inc
            const int old = atomicAdd((int*)ws + WS_CNT, 1);
            isLast = (old == 63);
        }
        __syncthreads();

        // ---- finisher: last Z-block computes losses + isqa_pred ----
        if (isLast && tid < 64) {
            __threadfence();                 // acquire all blocks' zg/logits
            const float zg = ws[WS_ZG + tid];
            const float l0 = ws[WS_LOGITS + tid * 2 + 0];
            const float l1 = ws[WS_LOGITS + tid * 2 + 1];
            const float m  = fmaxf(l0, l1);
            const float lse = m + __logf(__expf(l0 - m) + __expf(l1 - m));
            const int   y   = isqa[tid];
            const float li  = lse - (y ? l1 : l0);
            float s1 = zg, s2 = li;
            #pragma unroll
            for (int d = 32; d; d >>= 1) {
                s1 += __shfl_xor(s1, d);
                s2 += __shfl_xor(s2, d);
            }
            out[OUT_ISQA_PRED + tid] = (l1 > l0) ? 1.0f : 0.0f;
            if (tid == 0) {
                out[OUT_CRF_LOSS]  = s1 * (1.0f / 64.0f);
                out[OUT_ISQA_LOSS] = s2 * (1.0f / 64.0f);
            }
        }
    } else {
        // ================= V-block: batches 4*(blk-64) .. +3 =================
        const int bv = blk - 64;
        float* sfT = smemf;                                    // 8192 + 16 pad
        unsigned int* bpw = (unsigned int*)(smemf + 8208);     // 4 x 512 words
        {   // stage transposed feats for 4 batches
            float4* d4 = (float4*)sfT;
            const float4* s4 = (const float4*)(ws + WS_FEATST) + bv * 4 * 512;
            #pragma unroll
            for (int n = 0; n < 8; ++n) d4[tid + 256 * n] = s4[tid + 256 * n];
        }
        if (tid < 4) ((float4*)(sfT + 8192))[tid & 3] =
            make_float4(0.f, 0.f, 0.f, 0.f);                   // pad
        __syncthreads();

        const int w    = tid >> 6;
        const int lane = tid & 63;
        const int j    = lane & 3;
        const int b    = bv * 4 + w;
        const int sh8j = 8 * j;

        const float tc0 = trans[0*4+j], tc1 = trans[1*4+j];
        const float tc2 = trans[2*4+j], tc3 = trans[3*4+j];
        const float tSj = trans[START*4+j];
        const float tjs = trans[j*4 + STOP];

        const float4* colT4 = (const float4*)(sfT + w * 2048 + j * 512);
        uint4* bpq = (uint4*)(bpw + w * 512);

        float4 A  = colT4[0];        // t 0..3
        float4 Bq = colT4[1];        // t 4..7
        float4 B2 = colT4[2];        // t 8..11
        float d = A.x + tSj;
        {
            const unsigned int W1 = vstep(d, A.y, tc0, tc1, tc2, tc3, sh8j);
            const unsigned int W2 = vstep(d, A.z, tc0, tc1, tc2, tc3, sh8j);
            const unsigned int W3 = vstep(d, A.w, tc0, tc1, tc2, tc3, sh8j);
            if (lane == 0) bpq[0] = make_uint4(0x03020100u, W1, W2, W3);
        }
        for (int g = 1; g < 128; ++g) {
            const float4 Cq = colT4[g + 2];   // prefetch (pad covers g>=126)
            const unsigned int W0 = vstep(d, Bq.x, tc0, tc1, tc2, tc3, sh8j);
            const unsigned int W1 = vstep(d, Bq.y, tc0, tc1, tc2, tc3, sh8j);
            const unsigned int W2 = vstep(d, Bq.z, tc0, tc1, tc2, tc3, sh8j);
            const unsigned int W3 = vstep(d, Bq.w, tc0, tc1, tc2, tc3, sh8j);
            if (lane == 0) bpq[g] = make_uint4(W0, W1, W2, W3);
            Bq = B2; B2 = Cq;
        }

        // last_tag (first-index-wins argmax over states)
        const float vj = d + tjs;
        const float z0 = dppf<0x00>(vj), z1 = dppf<0x55>(vj);
        const float z2 = dppf<0xAA>(vj), z3 = dppf<0xFF>(vj);
        float m01 = z0; unsigned int i01 = 0;
        if (z1 > m01) { m01 = z1; i01 = 1; }
        float m23 = z2; unsigned int i23 = 2;
        if (z3 > m23) { m23 = z3; i23 = 3; }
        const unsigned int lt = (m23 > m01) ? i23 : i01;

        __syncthreads();

        // backtrack: chunk map composition via v_perm_b32
        const uint4 wv0 = bpq[lane * 2 + 0];   // t = 8L..8L+3
        const uint4 wv1 = bpq[lane * 2 + 1];   // t = 8L+4..8L+7
        unsigned int wk[8] = {wv0.x, wv0.y, wv0.z, wv0.w, wv1.x, wv1.y, wv1.z, wv1.w};
        unsigned int G = wk[7];
        #pragma unroll
        for (int k = 6; k >= 0; --k)
            G = __builtin_amdgcn_perm(0u, wk[k], G);     // f_k ∘ G
        unsigned int Sm = G;
        #pragma unroll
        for (int dd = 1; dd < 64; dd <<= 1) {
            const int srcl = lane + dd;
            const unsigned int oth = __shfl(Sm, (srcl < 64) ? srcl : 63);
            if (srcl < 64) Sm = __builtin_amdgcn_perm(0u, Sm, oth);  // Sm ∘ oth
        }
        unsigned int emap = __shfl(Sm, (lane < 63) ? lane + 1 : 63);
        if (lane == 63) emap = 0x03020100u;
        unsigned int cur = (emap >> (8 * lt)) & 3u;

        float tg[8];
        tg[7] = (float)cur;
        #pragma unroll
        for (int k = 7; k >= 1; --k) {
            cur = (wk[k] >> (8 * cur)) & 3u;
            tg[k - 1] = (float)cur;
        }
        float4* op = (float4*)(out + OUT_CRF_PRED + b * S + lane * 8);
        op[0] = make_float4(tg[0], tg[1], tg[2], tg[3]);
        op[1] = make_float4(tg[4], tg[5], tg[6], tg[7]);
    }
}

// ---------------------------------------------------------------------------
extern "C" void kernel_launch(void* const* d_in, const int* in_sizes, int n_in,
                              void* d_out, int out_size, void* d_ws, size_t ws_size,
                              hipStream_t stream)
{
    const float* emb    = (const float*)d_in[0];
    const int*   ans    = (const int*)d_in[1];
    const int*   isqa   = (const int*)d_in[2];
    const float* fc2_W  = (const float*)d_in[3];
    const float* fc2_b  = (const float*)d_in[4];
    const float* crf_W  = (const float*)d_in[5];
    const float* crf_b  = (const float*)d_in[6];
    const float* trans  = (const float*)d_in[7];
    float* out = (float*)d_out;
    float* ws  = (float*)d_ws;

    feats_kernel<<<1024, 256, 0, stream>>>(emb, crf_W, crf_b, ws);
    crf_kernel<<<80, 256, 0, stream>>>(ans, isqa, emb, fc2_W, fc2_b, trans, ws, out);
}